// Round 10
// baseline (320.510 us; speedup 1.0000x reference)
//
#include <hip/hip_runtime.h>

// ---------------------------------------------------------------------------
// SwitchMLP (top-1 MoE, SwiGLU) for MI355X / gfx950.  S=1024 B=4 DIM=768
// HID=2048 E=8, f32 in/out.
//
// GEMM operands pre-staged in f16 MFMA fragment order (1 KB "cells").
//   convert: w1/w2/w3 f32 [K][N] -> swizzled f16 B-operand cells; 3 launches.
//            32k x 256n tiles: global reads AND writes are 1 KB contiguous
//            per wave instruction; LDS f32 stride 258 (float2 writes,
//            transpose reads <=2-way banks).
//   router : atomic-free; phase A logits/argmax/prob, phase B ballot lists.
//   gather : X rows -> Ag (A-operand cells, zero-padded to 64-row tiles)
//   gemm1  : h = silu(A@W1)*(A@W2); block 128m x 64n, wave 64m x 32n;
//            staging via global_load_lds width-16, double-buffered,
//            1 barrier/K-step; grid (32,4,8) + by-loop (no dead blocks).
//   gemm2  : out[tok] = bf16_rne(Hs@W3) * prob[tok]; block 64m x 128n;
//            A via global_load_lds (shared), W3 direct global->reg dbuf.
//
// Fragment layouts (HW-validated):
//   A-op: lane l holds A[m=l&15][k=(l>>4)*8+j]   (cell = 16m x 32k = 512 f16)
//   B-op: lane l holds B[k=(l>>4)*8+j][n=l&15]   (cell = 32k x 16n = 512 f16)
//   C/D : lane l holds C[row=(l>>4)*4+r][col=l&15]
// ---------------------------------------------------------------------------

#define T_TOK 4096
#define DIM   768
#define HID   2048
#define NE    8
#define ECAP  1024           // per-expert token capacity (~24 sigma margin)

#define KB1 24               // DIM/32  k-cells, gemm1
#define NB1 128              // HID/16  n-cells, w1/w2
#define KB2 64               // HID/32  k-cells, gemm2
#define NB2 48               // DIM/16  n-cells, w3
#define MBC 64               // ECAP/16 m-cells per expert

typedef _Float16 f16x8 __attribute__((ext_vector_type(8)));
typedef float    f32x4 __attribute__((ext_vector_type(4)));

#define AS1 __attribute__((address_space(1)))
#define AS3 __attribute__((address_space(3)))

// Async global->LDS, 16 B per lane.  LDS dest is wave-uniform base + lane*16;
// global src is per-lane.  Counted by vmcnt; drained by the compiler's
// waitcnt before s_barrier.
__device__ __forceinline__ void gload_lds16(const _Float16* g, _Float16* l) {
    __builtin_amdgcn_global_load_lds((const AS1 unsigned int*)g,
                                     (AS3 unsigned int*)l, 16, 0, 0);
}

__device__ __forceinline__ float bf16_rne(float v) {
    unsigned u = __float_as_uint(v);
    unsigned r = (u + 0x7fffu + ((u >> 16) & 1u)) & 0xffff0000u;
    return __uint_as_float(r);
}

// ---------------------------------------------------------------------------
// Convert+swizzle one 32k x 256n tile into B-operand cells.
// Load: wave w covers rows w*8..w*8+7, lane l cols 4l..4l+3 -> every global
// read instr is a full row segment = 1 KB contiguous.  LDS [32][258] f32:
// float2 writes (aligned, linear); transpose reads (fq*8+j)*258 + nbl*16+fr
// hit each bank with exactly 2 lanes (8*258 mod 32 = 16).  Store: wave w
// emits n-cells 4w..4w+3 of k-cell kgrp; lane l writes cell-lane l -> every
// store instr is 1 KB contiguous.
__device__ __forceinline__ void convert_tile32(
    const float* __restrict__ src, _Float16* __restrict__ dst,
    float* Lt, int N, int KBc, int ngrp, int kgrp)
{
    const int t = threadIdx.x, w = t >> 6, l = t & 63;
    const float* p = src + (size_t)(kgrp * 32 + w * 8) * N + ngrp * 256 + 4 * l;
    float4 v[8];
#pragma unroll
    for (int j = 0; j < 8; ++j) v[j] = *(const float4*)(p + (size_t)j * N);
#pragma unroll
    for (int j = 0; j < 8; ++j) {
        float* row = &Lt[(w * 8 + j) * 258 + 4 * l];
        *(float2*)(row)     = make_float2(v[j].x, v[j].y);
        *(float2*)(row + 2) = make_float2(v[j].z, v[j].w);
    }
    __syncthreads();

    const int fr = l & 15, fq = l >> 4;
#pragma unroll
    for (int i = 0; i < 4; ++i) {
        const int nbl = w * 4 + i;
        f16x8 h;
#pragma unroll
        for (int j = 0; j < 8; ++j)
            h[j] = (_Float16)Lt[(fq * 8 + j) * 258 + nbl * 16 + fr];
        const int nb = ngrp * 16 + nbl;
        *(f16x8*)(dst + ((size_t)nb * KBc + kgrp) * 512 + l * 8) = h;
    }
}

__global__ __launch_bounds__(256) void moe_convert_w1_kernel(
    const float* __restrict__ w1, _Float16* __restrict__ w1s)
{
    __shared__ float Lt[32 * 258];
    const int e = blockIdx.x / 192, tile = blockIdx.x % 192;
    convert_tile32(w1 + (size_t)e * DIM * HID, w1s + (size_t)e * NB1 * KB1 * 512,
                   Lt, HID, KB1, tile & 7, tile >> 3);
}

__global__ __launch_bounds__(256) void moe_convert_w2_kernel(
    const float* __restrict__ w2, _Float16* __restrict__ w2s)
{
    __shared__ float Lt[32 * 258];
    const int e = blockIdx.x / 192, tile = blockIdx.x % 192;
    convert_tile32(w2 + (size_t)e * DIM * HID, w2s + (size_t)e * NB1 * KB1 * 512,
                   Lt, HID, KB1, tile & 7, tile >> 3);
}

__global__ __launch_bounds__(256) void moe_convert_w3_kernel(
    const float* __restrict__ w3, _Float16* __restrict__ w3s)
{
    __shared__ float Lt[32 * 258];
    const int e = blockIdx.x / 192, tile = blockIdx.x % 192;
    convert_tile32(w3 + (size_t)e * HID * DIM, w3s + (size_t)e * NB2 * KB2 * 512,
                   Lt, DIM, KB2, tile % 3, tile / 3);
}

// ---------------------------------------------------------------------------
// Router phase A: one wave per token, NO atomics.  Lane l computes the f64
// partial for expert e=l>>3 over contiguous dims (l&7)*96..+95; reduce over
// dim-groups (3 f64 shuffles); butterflies over 8/16/32 give global max /
// argmax (lowest-index tie-break) / softmax denom.  Writes probs, maxind.
__global__ __launch_bounds__(256) void moe_router_kernel(
    const float* __restrict__ X, const float* __restrict__ rw,
    const float* __restrict__ rb, float* __restrict__ probs,
    int* __restrict__ maxind)
{
    const int t = blockIdx.x * 4 + (threadIdx.x >> 6);
    const int l = threadIdx.x & 63;
    const int e = l >> 3;                 // this lane's expert
    const int g = l & 7;                  // dim-chunk
    const float* x = X + (size_t)t * DIM + g * 96;
    const float* w = rw + e;

    double s0 = 0.0, s1 = 0.0;
#pragma unroll
    for (int j4 = 0; j4 < 24; ++j4) {
        const float4 xv = *(const float4*)(x + j4 * 4);
        const int d = (g * 96 + j4 * 4) * NE;
        s0 += (double)xv.x * (double)w[d];
        s1 += (double)xv.y * (double)w[d + NE];
        s0 += (double)xv.z * (double)w[d + 2 * NE];
        s1 += (double)xv.w * (double)w[d + 3 * NE];
    }
    double s = s0 + s1;
    s += __shfl_xor(s, 1, 64);
    s += __shfl_xor(s, 2, 64);
    s += __shfl_xor(s, 4, 64);
    s += (double)rb[e];

    double m = s; int mi = e;
#pragma unroll
    for (int o = 8; o <= 32; o <<= 1) {
        const double om = __shfl_xor(m, o, 64);
        const int   omi = __shfl_xor(mi, o, 64);
        if (om > m || (om == m && omi < mi)) { m = om; mi = omi; }
    }
    float ex = __expf((float)(s - m));
#pragma unroll
    for (int o = 8; o <= 32; o <<= 1) ex += __shfl_xor(ex, o, 64);

    if (l == 0) { probs[t] = 1.0f / ex; maxind[t] = mi; }
}

// ---------------------------------------------------------------------------
// Router phase B: one block per expert.  Ballot-based stream compaction of
// maxind -> lists[e] (token-sorted), counts[e].  No global atomics.
__global__ __launch_bounds__(256) void moe_lists_kernel(
    const int* __restrict__ maxind, int* __restrict__ counts,
    int* __restrict__ lists)
{
    const int e = blockIdx.x;
    const int tid = threadIdx.x, wid = tid >> 6, lane = tid & 63;
    __shared__ int wsum[4];
    int* dst = lists + e * T_TOK;
    int base = 0;
    for (int t0 = 0; t0 < T_TOK; t0 += 256) {
        const int t = t0 + tid;
        const bool pred = (maxind[t] == e);
        const unsigned long long bal = __ballot(pred);
        const int prefix = __popcll(bal & ((1ull << lane) - 1ull));
        if (lane == 0) wsum[wid] = __popcll(bal);
        __syncthreads();
        int woff = 0;
#pragma unroll
        for (int w2 = 0; w2 < 4; ++w2)
            if (w2 < wid) woff += wsum[w2];
        const int tot = wsum[0] + wsum[1] + wsum[2] + wsum[3];
        if (pred) dst[base + woff + prefix] = t;
        base += tot;
        __syncthreads();                  // wsum reused next iteration
    }
    if (tid == 0) counts[e] = base;
}

// ---------------------------------------------------------------------------
// Gather X rows per expert into A-operand cells (f16), zero-padding rows
// beyond cnt up to the 64-row tile boundary.
__global__ __launch_bounds__(256) void moe_gather_kernel(
    const float* __restrict__ X, const int* __restrict__ lists,
    const int* __restrict__ counts, _Float16* __restrict__ Ag)
{
    const int e = blockIdx.z;
    int cnt = counts[e]; if (cnt > ECAP) cnt = ECAP;
    const int mgrp = blockIdx.y;
    if (mgrp * 64 >= ((cnt + 63) & ~63)) return;
    const int t = threadIdx.x, w = t >> 6, l = t & 63;
    const int mb = mgrp * 4 + w;
    const int m  = mb * 16 + (l & 15);
    const bool valid = (m < cnt);
    const int tok = valid ? lists[e * T_TOK + m] : 0;
    const float* xr = X + (size_t)tok * DIM + (l >> 4) * 8;
#pragma unroll
    for (int i = 0; i < 4; ++i) {
        const int kb = blockIdx.x * 4 + i;
        float4 a = make_float4(0.f, 0.f, 0.f, 0.f), b = a;
        if (valid) {
            a = *(const float4*)(xr + kb * 32);
            b = *(const float4*)(xr + kb * 32 + 4);
        }
        f16x8 h;
        h[0] = (_Float16)a.x; h[1] = (_Float16)a.y; h[2] = (_Float16)a.z; h[3] = (_Float16)a.w;
        h[4] = (_Float16)b.x; h[5] = (_Float16)b.y; h[6] = (_Float16)b.z; h[7] = (_Float16)b.w;
        *(f16x8*)(Ag + ((size_t)(e * MBC + mb) * KB1 + kb) * 512 + l * 8) = h;
    }
}

// ---------------------------------------------------------------------------
// GEMM1: block = 128m x 64n (both W1,W2), wave = 64m x 32n.  Grid (32,4,8):
// by-loop (by += 4) so every launched block does work -> true 4 blocks/CU.
// Per K-step the block stages 16 cells (8 A + 4 W1 + 4 W2 = 16 KB) into LDS
// via global_load_lds (wave w stages cells 4w..4w+3), double-buffered, ONE
// barrier per step at the END.  Epilogue transpose buffer ALIASES Ls; a
// trailing barrier protects it from the next by-iteration's STAGE.
__global__ __launch_bounds__(256, 4) void moe_gemm1_kernel(
    const _Float16* __restrict__ Ag, const _Float16* __restrict__ w1s,
    const _Float16* __restrict__ w2s, const int* __restrict__ counts,
    _Float16* __restrict__ Hs)
{
    const int e = blockIdx.z;
    int cnt = counts[e]; if (cnt > ECAP) cnt = ECAP;
    const int bx = blockIdx.x;                    // 64n tile
    const int t = threadIdx.x, w = t >> 6, l = t & 63;
    const int wm = w & 1, wn = w >> 1;
    const int c0s = w * 4;

    __shared__ _Float16 Ls[2][16 * 512];          // 32 KB staging (epilogue aliases)

    for (int by = blockIdx.y; by * 128 < cnt; by += 4) {
        // staging sources: wave w owns cells 4w..4w+3
        //   cells 0-7: A (m-cells by*8+c); 8-11: W1 n-cells bx*4+(c-8); 12-15: W2
        const _Float16* gsrc[4];
#pragma unroll
        for (int i = 0; i < 4; ++i) {
            const int c = c0s + i;
            if (c < 8)
                gsrc[i] = Ag  + ((size_t)((e * MBC + by * 8 + c) * KB1)) * 512;
            else if (c < 12)
                gsrc[i] = w1s + ((size_t)((e * NB1 + bx * 4 + (c - 8)) * KB1)) * 512;
            else
                gsrc[i] = w2s + ((size_t)((e * NB1 + bx * 4 + (c - 12)) * KB1)) * 512;
            gsrc[i] += (size_t)l * 8;             // per-lane 16 B
        }

        f32x4 acc1[4][2], acc2[4][2];
        const f32x4 zero = {0.f, 0.f, 0.f, 0.f};
#pragma unroll
        for (int i = 0; i < 4; ++i)
#pragma unroll
            for (int j = 0; j < 2; ++j) { acc1[i][j] = zero; acc2[i][j] = zero; }

        auto STAGE = [&](int kb, _Float16* Lb) {
#pragma unroll
            for (int i = 0; i < 4; ++i)
                gload_lds16(gsrc[i] + (size_t)kb * 512, Lb + (c0s + i) * 512);
        };

        STAGE(0, &Ls[0][0]);
        __syncthreads();                          // buffer 0 ready
        for (int kb = 0; kb < KB1; ++kb) {
            _Float16* Lb = &Ls[kb & 1][0];
            if (kb + 1 < KB1) STAGE(kb + 1, &Ls[(kb + 1) & 1][0]);  // in flight

            f16x8 a[4], p[2], q[2];
#pragma unroll
            for (int i = 0; i < 4; ++i)
                a[i] = *(const f16x8*)(Lb + (wm * 4 + i) * 512 + l * 8);
#pragma unroll
            for (int j = 0; j < 2; ++j) {
                p[j] = *(const f16x8*)(Lb + (8  + wn * 2 + j) * 512 + l * 8);
                q[j] = *(const f16x8*)(Lb + (12 + wn * 2 + j) * 512 + l * 8);
            }
#pragma unroll
            for (int i = 0; i < 4; ++i)
#pragma unroll
                for (int j = 0; j < 2; ++j) {
                    acc1[i][j] = __builtin_amdgcn_mfma_f32_16x16x32_f16(a[i], p[j], acc1[i][j], 0, 0, 0);
                    acc2[i][j] = __builtin_amdgcn_mfma_f32_16x16x32_f16(a[i], q[j], acc2[i][j], 0, 0, 0);
                }
            __syncthreads();                      // drains next-buffer loads
        }

        // epilogue: silu(h1)*h2 -> f16; C-layout -> A-layout via per-wave LDS
        // region aliased onto Ls (64 rows x 40 f16 = 5120 B per wave).
        _Float16* Ep = &Ls[0][0] + (size_t)w * (64 * 40);
        const int fq = l >> 4, fr = l & 15;
#pragma unroll
        for (int i = 0; i < 4; ++i)
#pragma unroll
            for (int j = 0; j < 2; ++j)
#pragma unroll
                for (int r = 0; r < 4; ++r) {
                    const float h1 = acc1[i][j][r], h2 = acc2[i][j][r];
                    const float s  = h1 / (1.f + __expf(-h1)) * h2;
                    Ep[(i * 16 + fq * 4 + r) * 40 + j * 16 + fr] = (_Float16)s;
                }
        __syncthreads();
        const int kbH = bx * 2 + wn;              // this wave's 32-wide hid cell
#pragma unroll
        for (int i = 0; i < 4; ++i) {
            f16x8 v = *(const f16x8*)&Ep[(i * 16 + fr) * 40 + fq * 8];
            *(f16x8*)(Hs + ((size_t)((e * MBC + by * 8 + wm * 4 + i) * KB2 + kbH)) * 512 + l * 8) = v;
        }
        __syncthreads();                          // Ep safe before next STAGE
    }
}

// ---------------------------------------------------------------------------
// GEMM2: block = 64m x 128n, wave = 64m x 32n, K=2048.  W3 cells wave-private
// -> direct global, register double-buffered (named vB0/vB1).  A cells shared
// by all 4 waves -> LDS via global_load_lds (2 k-cells x 4 m-cells = 8 KB,
// dbuf), one barrier per 2 K-steps at the END of the step.
// Epilogue: bf16_rne(acc) * prob, scatter f32 by token.
__global__ __launch_bounds__(256, 4) void moe_gemm2_kernel(
    const _Float16* __restrict__ Hs, const _Float16* __restrict__ w3s,
    const int* __restrict__ lists, const int* __restrict__ counts,
    const float* __restrict__ probs, float* __restrict__ out)
{
    const int e = blockIdx.z;
    int cnt = counts[e]; if (cnt > ECAP) cnt = ECAP;
    const int by = blockIdx.y, bx = blockIdx.x;   // by: 64m, bx: 128n
    if (by * 64 >= cnt) return;
    const int t = threadIdx.x, w = t >> 6, l = t & 63;

    __shared__ _Float16 La[2][8 * 512];           // 16 KB: 2 k-cells x 4 m-cells

    // A staging source: wave w stages m-cell w (for both k-cells of a step)
    const _Float16* Asrc = Hs + ((size_t)((e * MBC + by * 4 + w) * KB2)) * 512 + l * 8;
    const int nb0 = e * NB2 + bx * 8 + w * 2;
    const _Float16* Bb = w3s + ((size_t)nb0 * KB2) * 512 + l * 8;

    f32x4 acc[4][2];
    const f32x4 zero = {0.f, 0.f, 0.f, 0.f};
#pragma unroll
    for (int i = 0; i < 4; ++i) { acc[i][0] = zero; acc[i][1] = zero; }

    f16x8 vB0[4], vB1[4];    // W3 frags, double-buffered: [u*2+j]

    auto STAGE_A = [&](int s, _Float16* Lb) {
        gload_lds16(Asrc + (size_t)(2 * s)     * 512, Lb +      w  * 512);
        gload_lds16(Asrc + (size_t)(2 * s + 1) * 512, Lb + (4 + w) * 512);
    };
    auto GB = [&](f16x8* vB, int s) {
#pragma unroll
        for (int u = 0; u < 2; ++u)
#pragma unroll
            for (int j = 0; j < 2; ++j)
                vB[u * 2 + j] = *(const f16x8*)(Bb + ((size_t)(j * KB2 + 2 * s + u)) * 512);
    };
    auto STEP = [&](int s, const f16x8* curB, f16x8* nxtB,
                    _Float16* Lb, _Float16* Ln) {
        if (s + 1 < KB2 / 2) { STAGE_A(s + 1, Ln); GB(nxtB, s + 1); }
#pragma unroll
        for (int u = 0; u < 2; ++u) {
            f16x8 a[4];
#pragma unroll
            for (int i = 0; i < 4; ++i)
                a[i] = *(const f16x8*)(Lb + (u * 4 + i) * 512 + l * 8);
#pragma unroll
            for (int i = 0; i < 4; ++i)
#pragma unroll
                for (int j = 0; j < 2; ++j)
                    acc[i][j] = __builtin_amdgcn_mfma_f32_16x16x32_f16(a[i], curB[u * 2 + j], acc[i][j], 0, 0, 0);
        }
        __syncthreads();                          // drains next-buffer loads
    };

    STAGE_A(0, &La[0][0]); GB(vB0, 0);
    __syncthreads();                              // buffer 0 ready
    for (int s2 = 0; s2 < KB2 / 2; s2 += 2) {     // 32 steps, unroll-2 for static vB
        STEP(s2,     vB0, vB1, &La[0][0], &La[1][0]);
        STEP(s2 + 1, vB1, vB0, &La[1][0], &La[0][0]);
    }

    const int* list = lists + e * T_TOK;
    const int fq = l >> 4, fr = l & 15;
    const int c0 = bx * 128 + w * 32;
#pragma unroll
    for (int i = 0; i < 4; ++i)
#pragma unroll
        for (int r = 0; r < 4; ++r) {
            const int m = by * 64 + i * 16 + fq * 4 + r;
            if (m < cnt) {
                const int tok = list[m];
                const float pb = probs[tok];
                float* orow = out + (size_t)tok * DIM + c0 + fr;
                orow[0]  = bf16_rne(acc[i][0][r]) * pb;
                orow[16] = bf16_rne(acc[i][1][r]) * pb;
            }
        }
}

// ---------------------------------------------------------------------------
extern "C" void kernel_launch(void* const* d_in, const int* in_sizes, int n_in,
                              void* d_out, int out_size, void* d_ws, size_t ws_size,
                              hipStream_t stream) {
    const float* X  = (const float*)d_in[0];
    const float* rw = (const float*)d_in[1];
    const float* rb = (const float*)d_in[2];
    const float* w1 = (const float*)d_in[3];
    const float* w2 = (const float*)d_in[4];
    const float* w3 = (const float*)d_in[5];
    float* out = (float*)d_out;

    // workspace layout (bytes); total ~121.6 MB
    char* ws = (char*)d_ws;
    int*      counts = (int*)(ws + 0);
    int*      lists  = (int*)(ws + 256);
    float*    probs  = (float*)(ws + 131328);
    const size_t WSZ = 25165824;  // each swizzled weight: 8*NB*KB*512*2 B
    _Float16* w1s = (_Float16*)(ws + 147712);
    _Float16* w2s = (_Float16*)(ws + 147712 + WSZ);
    _Float16* w3s = (_Float16*)(ws + 147712 + 2 * WSZ);
    _Float16* Ag  = (_Float16*)(ws + 147712 + 3 * WSZ);              // 12.6 MB
    _Float16* Hs  = (_Float16*)(ws + 147712 + 3 * WSZ + 12582912);   // 33.6 MB
    // maxind aliases the head of Ag: written by router, fully consumed by
    // moe_lists_kernel BEFORE moe_gather_kernel writes Ag (same stream).
    int* maxind = (int*)Ag;

    hipLaunchKernelGGL(moe_convert_w1_kernel, dim3(1536), dim3(256), 0, stream, w1, w1s);
    hipLaunchKernelGGL(moe_convert_w2_kernel, dim3(1536), dim3(256), 0, stream, w2, w2s);
    hipLaunchKernelGGL(moe_convert_w3_kernel, dim3(1536), dim3(256), 0, stream, w3, w3s);
    hipLaunchKernelGGL(moe_router_kernel, dim3(T_TOK / 4), dim3(256), 0, stream,
                       X, rw, rb, probs, maxind);
    hipLaunchKernelGGL(moe_lists_kernel, dim3(NE), dim3(256), 0, stream,
                       maxind, counts, lists);
    hipLaunchKernelGGL(moe_gather_kernel, dim3(6, 16, 8), dim3(256), 0, stream,
                       X, lists, counts, Ag);
    hipLaunchKernelGGL(moe_gemm1_kernel, dim3(32, 4, 8), dim3(256), 0, stream,
                       Ag, w1s, w2s, counts, Hs);
    hipLaunchKernelGGL(moe_gemm2_kernel, dim3(6, 16, 8), dim3(256), 0, stream,
                       Hs, w3s, lists, counts, probs, out);
}

// Round 11
// 314.760 us; speedup vs baseline: 1.0183x; 1.0183x over previous
//
#include <hip/hip_runtime.h>

// ---------------------------------------------------------------------------
// SwitchMLP (top-1 MoE, SwiGLU) for MI355X / gfx950.  S=1024 B=4 DIM=768
// HID=2048 E=8, f32 in/out.
//
// GEMM operands pre-staged in f16 MFMA fragment order (1 KB "cells").
//   convert: w1/w2/w3 f32 [K][N] -> swizzled f16 B-operand cells; 3 launches
//            (round-0 structure, best measured of 4 variants).
//   router : atomic-free; phase A logits/argmax/prob, phase B ballot lists.
//   gather : X rows -> Ag (A-operand cells, zero-padded to 64-row tiles)
//   gemm1  : h = silu(A@W1)*(A@W2); block 128m x 64n, wave 64m x 32n;
//            A via global_load_lds (shared 2x, dbuf, 1 barrier/K-step);
//            W1/W2 DIRECT global->reg dbuf (shared only 2x -> LDS staging
//            was pure LDS-pipe overhead: 12 -> 6 LDS ops per wave-step).
//   gemm2  : out[tok] = bf16_rne(Hs@W3) * prob[tok]; block 64m x 128n;
//            A via global_load_lds (shared), W3 direct global->reg dbuf.
//
// Fragment layouts (HW-validated):
//   A-op: lane l holds A[m=l&15][k=(l>>4)*8+j]   (cell = 16m x 32k = 512 f16)
//   B-op: lane l holds B[k=(l>>4)*8+j][n=l&15]   (cell = 32k x 16n = 512 f16)
//   C/D : lane l holds C[row=(l>>4)*4+r][col=l&15]
// ---------------------------------------------------------------------------

#define T_TOK 4096
#define DIM   768
#define HID   2048
#define NE    8
#define ECAP  1024           // per-expert token capacity (~24 sigma margin)

#define KB1 24               // DIM/32  k-cells, gemm1
#define NB1 128              // HID/16  n-cells, w1/w2
#define KB2 64               // HID/32  k-cells, gemm2
#define NB2 48               // DIM/16  n-cells, w3
#define MBC 64               // ECAP/16 m-cells per expert

typedef _Float16 f16x8 __attribute__((ext_vector_type(8)));
typedef float    f32x4 __attribute__((ext_vector_type(4)));

#define AS1 __attribute__((address_space(1)))
#define AS3 __attribute__((address_space(3)))

// Async global->LDS, 16 B per lane.  LDS dest is wave-uniform base + lane*16;
// global src is per-lane.  Counted by vmcnt; drained by the compiler's
// waitcnt before s_barrier.
__device__ __forceinline__ void gload_lds16(const _Float16* g, _Float16* l) {
    __builtin_amdgcn_global_load_lds((const AS1 unsigned int*)g,
                                     (AS3 unsigned int*)l, 16, 0, 0);
}

__device__ __forceinline__ float bf16_rne(float v) {
    unsigned u = __float_as_uint(v);
    unsigned r = (u + 0x7fffu + ((u >> 16) & 1u)) & 0xffff0000u;
    return __uint_as_float(r);
}

// ---------------------------------------------------------------------------
// Convert+swizzle one 64k x 128n tile into B-operand cells (round-0 variant,
// best measured of 4 structures).  LDS f32 [k][n] stride 130.
__device__ __forceinline__ void convert_tile(
    const float* __restrict__ src, _Float16* __restrict__ dst,
    float* Lt, int N, int KBc, int ngrp, int kgrp)
{
    const int t  = threadIdx.x;
    const int c4 = (t & 31) * 4;         // f32 col within 128
    const int r0 = (t >> 5) * 8;         // first of 8 k-rows
    const float* p = src + (size_t)(kgrp * 64 + r0) * N + ngrp * 128 + c4;
    float4 v[8];
#pragma unroll
    for (int j = 0; j < 8; ++j) v[j] = *(const float4*)(p + (size_t)j * N);
#pragma unroll
    for (int j = 0; j < 8; ++j) {
        float* row = &Lt[(r0 + j) * 130 + c4];
        *(float2*)(row)     = make_float2(v[j].x, v[j].y);
        *(float2*)(row + 2) = make_float2(v[j].z, v[j].w);
    }
    __syncthreads();

    const int l = t & 63, w = t >> 6;
    const int fr = l & 15, fq = l >> 4;
#pragma unroll
    for (int i = 0; i < 4; ++i) {
        const int cell = w * 4 + i;      // 16 cells: 2 kbl x 8 nbl
        const int kbl = cell >> 3, nbl = cell & 7;
        f16x8 h;
#pragma unroll
        for (int j = 0; j < 8; ++j)
            h[j] = (_Float16)Lt[(kbl * 32 + fq * 8 + j) * 130 + nbl * 16 + fr];
        const int nb = ngrp * 8 + nbl, kb = kgrp * 2 + kbl;
        *(f16x8*)(dst + ((size_t)nb * KBc + kb) * 512 + l * 8) = h;
    }
}

__global__ __launch_bounds__(256) void moe_convert_w1_kernel(
    const float* __restrict__ w1, _Float16* __restrict__ w1s)
{
    __shared__ float Lt[64 * 130];
    const int e = blockIdx.x / 192, tile = blockIdx.x % 192;
    convert_tile(w1 + (size_t)e * DIM * HID, w1s + (size_t)e * NB1 * KB1 * 512,
                 Lt, HID, KB1, tile & 15, tile >> 4);
}

__global__ __launch_bounds__(256) void moe_convert_w2_kernel(
    const float* __restrict__ w2, _Float16* __restrict__ w2s)
{
    __shared__ float Lt[64 * 130];
    const int e = blockIdx.x / 192, tile = blockIdx.x % 192;
    convert_tile(w2 + (size_t)e * DIM * HID, w2s + (size_t)e * NB1 * KB1 * 512,
                 Lt, HID, KB1, tile & 15, tile >> 4);
}

__global__ __launch_bounds__(256) void moe_convert_w3_kernel(
    const float* __restrict__ w3, _Float16* __restrict__ w3s)
{
    __shared__ float Lt[64 * 130];
    const int e = blockIdx.x / 192, tile = blockIdx.x % 192;
    convert_tile(w3 + (size_t)e * HID * DIM, w3s + (size_t)e * NB2 * KB2 * 512,
                 Lt, DIM, KB2, tile % 6, tile / 6);
}

// ---------------------------------------------------------------------------
// Router phase A: one wave per token, NO atomics.  Lane l computes the f64
// partial for expert e=l>>3 over contiguous dims (l&7)*96..+95; reduce over
// dim-groups (3 f64 shuffles); butterflies over 8/16/32 give global max /
// argmax (lowest-index tie-break) / softmax denom.  Writes probs, maxind.
__global__ __launch_bounds__(256) void moe_router_kernel(
    const float* __restrict__ X, const float* __restrict__ rw,
    const float* __restrict__ rb, float* __restrict__ probs,
    int* __restrict__ maxind)
{
    const int t = blockIdx.x * 4 + (threadIdx.x >> 6);
    const int l = threadIdx.x & 63;
    const int e = l >> 3;                 // this lane's expert
    const int g = l & 7;                  // dim-chunk
    const float* x = X + (size_t)t * DIM + g * 96;
    const float* w = rw + e;

    double s0 = 0.0, s1 = 0.0;
#pragma unroll
    for (int j4 = 0; j4 < 24; ++j4) {
        const float4 xv = *(const float4*)(x + j4 * 4);
        const int d = (g * 96 + j4 * 4) * NE;
        s0 += (double)xv.x * (double)w[d];
        s1 += (double)xv.y * (double)w[d + NE];
        s0 += (double)xv.z * (double)w[d + 2 * NE];
        s1 += (double)xv.w * (double)w[d + 3 * NE];
    }
    double s = s0 + s1;
    s += __shfl_xor(s, 1, 64);
    s += __shfl_xor(s, 2, 64);
    s += __shfl_xor(s, 4, 64);
    s += (double)rb[e];

    double m = s; int mi = e;
#pragma unroll
    for (int o = 8; o <= 32; o <<= 1) {
        const double om = __shfl_xor(m, o, 64);
        const int   omi = __shfl_xor(mi, o, 64);
        if (om > m || (om == m && omi < mi)) { m = om; mi = omi; }
    }
    float ex = __expf((float)(s - m));
#pragma unroll
    for (int o = 8; o <= 32; o <<= 1) ex += __shfl_xor(ex, o, 64);

    if (l == 0) { probs[t] = 1.0f / ex; maxind[t] = mi; }
}

// ---------------------------------------------------------------------------
// Router phase B: one block per expert.  Ballot-based stream compaction of
// maxind -> lists[e] (token-sorted), counts[e].  No global atomics.
__global__ __launch_bounds__(256) void moe_lists_kernel(
    const int* __restrict__ maxind, int* __restrict__ counts,
    int* __restrict__ lists)
{
    const int e = blockIdx.x;
    const int tid = threadIdx.x, wid = tid >> 6, lane = tid & 63;
    __shared__ int wsum[4];
    int* dst = lists + e * T_TOK;
    int base = 0;
    for (int t0 = 0; t0 < T_TOK; t0 += 256) {
        const int t = t0 + tid;
        const bool pred = (maxind[t] == e);
        const unsigned long long bal = __ballot(pred);
        const int prefix = __popcll(bal & ((1ull << lane) - 1ull));
        if (lane == 0) wsum[wid] = __popcll(bal);
        __syncthreads();
        int woff = 0;
#pragma unroll
        for (int w2 = 0; w2 < 4; ++w2)
            if (w2 < wid) woff += wsum[w2];
        const int tot = wsum[0] + wsum[1] + wsum[2] + wsum[3];
        if (pred) dst[base + woff + prefix] = t;
        base += tot;
        __syncthreads();                  // wsum reused next iteration
    }
    if (tid == 0) counts[e] = base;
}

// ---------------------------------------------------------------------------
// Gather X rows per expert into A-operand cells (f16), zero-padding rows
// beyond cnt up to the 64-row tile boundary.
__global__ __launch_bounds__(256) void moe_gather_kernel(
    const float* __restrict__ X, const int* __restrict__ lists,
    const int* __restrict__ counts, _Float16* __restrict__ Ag)
{
    const int e = blockIdx.z;
    int cnt = counts[e]; if (cnt > ECAP) cnt = ECAP;
    const int mgrp = blockIdx.y;
    if (mgrp * 64 >= ((cnt + 63) & ~63)) return;
    const int t = threadIdx.x, w = t >> 6, l = t & 63;
    const int mb = mgrp * 4 + w;
    const int m  = mb * 16 + (l & 15);
    const bool valid = (m < cnt);
    const int tok = valid ? lists[e * T_TOK + m] : 0;
    const float* xr = X + (size_t)tok * DIM + (l >> 4) * 8;
#pragma unroll
    for (int i = 0; i < 4; ++i) {
        const int kb = blockIdx.x * 4 + i;
        float4 a = make_float4(0.f, 0.f, 0.f, 0.f), b = a;
        if (valid) {
            a = *(const float4*)(xr + kb * 32);
            b = *(const float4*)(xr + kb * 32 + 4);
        }
        f16x8 h;
        h[0] = (_Float16)a.x; h[1] = (_Float16)a.y; h[2] = (_Float16)a.z; h[3] = (_Float16)a.w;
        h[4] = (_Float16)b.x; h[5] = (_Float16)b.y; h[6] = (_Float16)b.z; h[7] = (_Float16)b.w;
        *(f16x8*)(Ag + ((size_t)(e * MBC + mb) * KB1 + kb) * 512 + l * 8) = h;
    }
}

// ---------------------------------------------------------------------------
// GEMM1: block = 128m x 64n (both W1,W2), wave = 64m x 32n.  Grid (32,8,8),
// early-exit for by*128 >= cnt (freed slots are cheap; round-10 by-loop
// serialized stragglers and regressed).
// A (8 cells/step, shared 2x) staged via global_load_lds, dbuf, 1 barrier
// per K-step.  W1/W2 cells (shared only 2x) read DIRECT global->reg,
// double-buffered (named p0/q0 vs p1/q1, static indexing): LDS pipe per
// wave-step drops from 12 ops to 6 (2 gload-writes + 4 ds_read_b128).
// Epilogue: silu(h1)*h2 -> f16, C->A layout via per-wave Ep LDS, -> Hs.
__global__ __launch_bounds__(256, 4) void moe_gemm1_kernel(
    const _Float16* __restrict__ Ag, const _Float16* __restrict__ w1s,
    const _Float16* __restrict__ w2s, const int* __restrict__ counts,
    _Float16* __restrict__ Hs)
{
    const int e = blockIdx.z;
    int cnt = counts[e]; if (cnt > ECAP) cnt = ECAP;
    const int by = blockIdx.y, bx = blockIdx.x;   // by: 128m, bx: 64n
    if (by * 128 >= cnt) return;
    const int t = threadIdx.x, w = t >> 6, l = t & 63;
    const int wm = w & 1, wn = w >> 1;

    __shared__ _Float16 Ls[2][8 * 512];           // 16 KB A staging
    __shared__ _Float16 Ep[4][64 * 40];           // 20 KB epilogue transpose

    // A staging: wave w stages m-cells 2w, 2w+1 of this by-tile
    const _Float16* Asrc0 = Ag + ((size_t)((e * MBC + by * 8 + 2 * w)     * KB1)) * 512 + l * 8;
    const _Float16* Asrc1 = Ag + ((size_t)((e * MBC + by * 8 + 2 * w + 1) * KB1)) * 512 + l * 8;
    // B direct: this wave's W1/W2 n-cells bx*4 + wn*2 + {0,1}
    const int nb0 = e * NB1 + bx * 4 + wn * 2;
    const _Float16* B1b = w1s + ((size_t)nb0 * KB1) * 512 + l * 8;
    const _Float16* B2b = w2s + ((size_t)nb0 * KB1) * 512 + l * 8;

    f32x4 acc1[4][2], acc2[4][2];
    const f32x4 zero = {0.f, 0.f, 0.f, 0.f};
#pragma unroll
    for (int i = 0; i < 4; ++i)
#pragma unroll
        for (int j = 0; j < 2; ++j) { acc1[i][j] = zero; acc2[i][j] = zero; }

    f16x8 p0[2], q0[2], p1[2], q1[2];

    auto STAGE_A = [&](int kb, _Float16* Lb) {
        gload_lds16(Asrc0 + (size_t)kb * 512, Lb + (2 * w)     * 512);
        gload_lds16(Asrc1 + (size_t)kb * 512, Lb + (2 * w + 1) * 512);
    };
    auto GB = [&](f16x8* p, f16x8* q, int kb) {
#pragma unroll
        for (int j = 0; j < 2; ++j) {
            p[j] = *(const f16x8*)(B1b + ((size_t)(j * KB1 + kb)) * 512);
            q[j] = *(const f16x8*)(B2b + ((size_t)(j * KB1 + kb)) * 512);
        }
    };
    auto STEP = [&](int kb, const f16x8* cp, const f16x8* cq,
                    f16x8* np, f16x8* nq) {
        _Float16* Lb = &Ls[kb & 1][0];
        if (kb + 1 < KB1) {
            STAGE_A(kb + 1, &Ls[(kb + 1) & 1][0]);   // async, in flight
            GB(np, nq, kb + 1);                       // reg dbuf, in flight
        }
        f16x8 a[4];
#pragma unroll
        for (int i = 0; i < 4; ++i)
            a[i] = *(const f16x8*)(Lb + (wm * 4 + i) * 512 + l * 8);
#pragma unroll
        for (int i = 0; i < 4; ++i)
#pragma unroll
            for (int j = 0; j < 2; ++j) {
                acc1[i][j] = __builtin_amdgcn_mfma_f32_16x16x32_f16(a[i], cp[j], acc1[i][j], 0, 0, 0);
                acc2[i][j] = __builtin_amdgcn_mfma_f32_16x16x32_f16(a[i], cq[j], acc2[i][j], 0, 0, 0);
            }
        __syncthreads();                              // drains next-buffer loads
    };

    STAGE_A(0, &Ls[0][0]); GB(p0, q0, 0);
    __syncthreads();                                  // buffer 0 ready
    for (int kb = 0; kb < KB1; kb += 2) {             // KB1=24 even
        STEP(kb,     p0, q0, p1, q1);
        STEP(kb + 1, p1, q1, p0, q0);
    }

    // epilogue: silu(h1)*h2 -> f16; C-layout -> A-layout via per-wave LDS
    const int fq = l >> 4, fr = l & 15;
#pragma unroll
    for (int i = 0; i < 4; ++i)
#pragma unroll
        for (int j = 0; j < 2; ++j)
#pragma unroll
            for (int r = 0; r < 4; ++r) {
                const float h1 = acc1[i][j][r], h2 = acc2[i][j][r];
                const float s  = h1 / (1.f + __expf(-h1)) * h2;
                Ep[w][(i * 16 + fq * 4 + r) * 40 + j * 16 + fr] = (_Float16)s;
            }
    __syncthreads();
    const int kbH = bx * 2 + wn;         // this wave's 32-wide hid cell
#pragma unroll
    for (int i = 0; i < 4; ++i) {
        f16x8 v = *(const f16x8*)&Ep[w][(i * 16 + fr) * 40 + fq * 8];
        *(f16x8*)(Hs + ((size_t)((e * MBC + by * 8 + wm * 4 + i) * KB2 + kbH)) * 512 + l * 8) = v;
    }
}

// ---------------------------------------------------------------------------
// GEMM2: block = 64m x 128n, wave = 64m x 32n, K=2048.  W3 cells wave-private
// -> direct global, register double-buffered (named vB0/vB1).  A cells shared
// by all 4 waves -> LDS via global_load_lds (2 k-cells x 4 m-cells = 8 KB,
// dbuf), one barrier per 2 K-steps at the END of the step.
// Epilogue: bf16_rne(acc) * prob, scatter f32 by token.
__global__ __launch_bounds__(256, 4) void moe_gemm2_kernel(
    const _Float16* __restrict__ Hs, const _Float16* __restrict__ w3s,
    const int* __restrict__ lists, const int* __restrict__ counts,
    const float* __restrict__ probs, float* __restrict__ out)
{
    const int e = blockIdx.z;
    int cnt = counts[e]; if (cnt > ECAP) cnt = ECAP;
    const int by = blockIdx.y, bx = blockIdx.x;   // by: 64m, bx: 128n
    if (by * 64 >= cnt) return;
    const int t = threadIdx.x, w = t >> 6, l = t & 63;

    __shared__ _Float16 La[2][8 * 512];           // 16 KB: 2 k-cells x 4 m-cells

    // A staging source: wave w stages m-cell w (for both k-cells of a step)
    const _Float16* Asrc = Hs + ((size_t)((e * MBC + by * 4 + w) * KB2)) * 512 + l * 8;
    const int nb0 = e * NB2 + bx * 8 + w * 2;
    const _Float16* Bb = w3s + ((size_t)nb0 * KB2) * 512 + l * 8;

    f32x4 acc[4][2];
    const f32x4 zero = {0.f, 0.f, 0.f, 0.f};
#pragma unroll
    for (int i = 0; i < 4; ++i) { acc[i][0] = zero; acc[i][1] = zero; }

    f16x8 vB0[4], vB1[4];    // W3 frags, double-buffered: [u*2+j]

    auto STAGE_A = [&](int s, _Float16* Lb) {
        gload_lds16(Asrc + (size_t)(2 * s)     * 512, Lb +      w  * 512);
        gload_lds16(Asrc + (size_t)(2 * s + 1) * 512, Lb + (4 + w) * 512);
    };
    auto GB = [&](f16x8* vB, int s) {
#pragma unroll
        for (int u = 0; u < 2; ++u)
#pragma unroll
            for (int j = 0; j < 2; ++j)
                vB[u * 2 + j] = *(const f16x8*)(Bb + ((size_t)(j * KB2 + 2 * s + u)) * 512);
    };
    auto STEP = [&](int s, const f16x8* curB, f16x8* nxtB,
                    _Float16* Lb, _Float16* Ln) {
        if (s + 1 < KB2 / 2) { STAGE_A(s + 1, Ln); GB(nxtB, s + 1); }
#pragma unroll
        for (int u = 0; u < 2; ++u) {
            f16x8 a[4];
#pragma unroll
            for (int i = 0; i < 4; ++i)
                a[i] = *(const f16x8*)(Lb + (u * 4 + i) * 512 + l * 8);
#pragma unroll
            for (int i = 0; i < 4; ++i)
#pragma unroll
                for (int j = 0; j < 2; ++j)
                    acc[i][j] = __builtin_amdgcn_mfma_f32_16x16x32_f16(a[i], curB[u * 2 + j], acc[i][j], 0, 0, 0);
        }
        __syncthreads();                          // drains next-buffer loads
    };

    STAGE_A(0, &La[0][0]); GB(vB0, 0);
    __syncthreads();                              // buffer 0 ready
    for (int s2 = 0; s2 < KB2 / 2; s2 += 2) {     // 32 steps, unroll-2 for static vB
        STEP(s2,     vB0, vB1, &La[0][0], &La[1][0]);
        STEP(s2 + 1, vB1, vB0, &La[1][0], &La[0][0]);
    }

    const int* list = lists + e * T_TOK;
    const int fq = l >> 4, fr = l & 15;
    const int c0 = bx * 128 + w * 32;
#pragma unroll
    for (int i = 0; i < 4; ++i)
#pragma unroll
        for (int r = 0; r < 4; ++r) {
            const int m = by * 64 + i * 16 + fq * 4 + r;
            if (m < cnt) {
                const int tok = list[m];
                const float pb = probs[tok];
                float* orow = out + (size_t)tok * DIM + c0 + fr;
                orow[0]  = bf16_rne(acc[i][0][r]) * pb;
                orow[16] = bf16_rne(acc[i][1][r]) * pb;
            }
        }
}

// ---------------------------------------------------------------------------
extern "C" void kernel_launch(void* const* d_in, const int* in_sizes, int n_in,
                              void* d_out, int out_size, void* d_ws, size_t ws_size,
                              hipStream_t stream) {
    const float* X  = (const float*)d_in[0];
    const float* rw = (const float*)d_in[1];
    const float* rb = (const float*)d_in[2];
    const float* w1 = (const float*)d_in[3];
    const float* w2 = (const float*)d_in[4];
    const float* w3 = (const float*)d_in[5];
    float* out = (float*)d_out;

    // workspace layout (bytes); total ~121.6 MB
    char* ws = (char*)d_ws;
    int*      counts = (int*)(ws + 0);
    int*      lists  = (int*)(ws + 256);
    float*    probs  = (float*)(ws + 131328);
    const size_t WSZ = 25165824;  // each swizzled weight: 8*NB*KB*512*2 B
    _Float16* w1s = (_Float16*)(ws + 147712);
    _Float16* w2s = (_Float16*)(ws + 147712 + WSZ);
    _Float16* w3s = (_Float16*)(ws + 147712 + 2 * WSZ);
    _Float16* Ag  = (_Float16*)(ws + 147712 + 3 * WSZ);              // 12.6 MB
    _Float16* Hs  = (_Float16*)(ws + 147712 + 3 * WSZ + 12582912);   // 33.6 MB
    // maxind aliases the head of Ag: written by router, fully consumed by
    // moe_lists_kernel BEFORE moe_gather_kernel writes Ag (same stream).
    int* maxind = (int*)Ag;

    hipLaunchKernelGGL(moe_convert_w1_kernel, dim3(1536), dim3(256), 0, stream, w1, w1s);
    hipLaunchKernelGGL(moe_convert_w2_kernel, dim3(1536), dim3(256), 0, stream, w2, w2s);
    hipLaunchKernelGGL(moe_convert_w3_kernel, dim3(1536), dim3(256), 0, stream, w3, w3s);
    hipLaunchKernelGGL(moe_router_kernel, dim3(T_TOK / 4), dim3(256), 0, stream,
                       X, rw, rb, probs, maxind);
    hipLaunchKernelGGL(moe_lists_kernel, dim3(NE), dim3(256), 0, stream,
                       maxind, counts, lists);
    hipLaunchKernelGGL(moe_gather_kernel, dim3(6, 16, 8), dim3(256), 0, stream,
                       X, lists, counts, Ag);
    hipLaunchKernelGGL(moe_gemm1_kernel, dim3(32, 8, 8), dim3(256), 0, stream,
                       Ag, w1s, w2s, counts, Hs);
    hipLaunchKernelGGL(moe_gemm2_kernel, dim3(6, 16, 8), dim3(256), 0, stream,
                       Hs, w3s, lists, counts, probs, out);
}

// Round 12
// 300.156 us; speedup vs baseline: 1.0678x; 1.0487x over previous
//
#include <hip/hip_runtime.h>

// ---------------------------------------------------------------------------
// SwitchMLP (top-1 MoE, SwiGLU) for MI355X / gfx950.  S=1024 B=4 DIM=768
// HID=2048 E=8, f32 in/out.
//
// GEMM operands pre-staged in f16 MFMA fragment order (1 KB "cells").
//   convert: w1/w2/w3 f32 [K][N] -> swizzled f16 B-operand cells; ONE launch
//            (round-0 structure, best measured of 4 variants).
//   router : atomic-free; phase A logits/argmax/prob, phase B ballot lists.
//   gather : X rows -> Ag (A-operand cells, zero-padded to 64-row tiles)
//   gemm1  : h = silu(A@W1)*(A@W2); block 128m x 64n, wave 64m x 32n;
//            ALL operands staged via global_load_lds width-16 (16 cells =
//            16 KB/step, dbuf, 1 barrier/K-step).  NOTE: do NOT mix direct
//            reg-destined B loads into this loop — the vmcnt wait for regs
//            also drains the async LDS prefetch (round-11 regression).
//   gemm2  : out[tok] = bf16_rne(Hs@W3) * prob[tok]; block 64m x 128n;
//            A via global_load_lds (shared), W3 direct global->reg dbuf.
//
// Fragment layouts (HW-validated):
//   A-op: lane l holds A[m=l&15][k=(l>>4)*8+j]   (cell = 16m x 32k = 512 f16)
//   B-op: lane l holds B[k=(l>>4)*8+j][n=l&15]   (cell = 32k x 16n = 512 f16)
//   C/D : lane l holds C[row=(l>>4)*4+r][col=l&15]
// ---------------------------------------------------------------------------

#define T_TOK 4096
#define DIM   768
#define HID   2048
#define NE    8
#define ECAP  1024           // per-expert token capacity (~24 sigma margin)

#define KB1 24               // DIM/32  k-cells, gemm1
#define NB1 128              // HID/16  n-cells, w1/w2
#define KB2 64               // HID/32  k-cells, gemm2
#define NB2 48               // DIM/16  n-cells, w3
#define MBC 64               // ECAP/16 m-cells per expert

typedef _Float16 f16x8 __attribute__((ext_vector_type(8)));
typedef float    f32x4 __attribute__((ext_vector_type(4)));

#define AS1 __attribute__((address_space(1)))
#define AS3 __attribute__((address_space(3)))

// Async global->LDS, 16 B per lane.  LDS dest is wave-uniform base + lane*16;
// global src is per-lane.  Counted by vmcnt; drained by the compiler's
// waitcnt before s_barrier.
__device__ __forceinline__ void gload_lds16(const _Float16* g, _Float16* l) {
    __builtin_amdgcn_global_load_lds((const AS1 unsigned int*)g,
                                     (AS3 unsigned int*)l, 16, 0, 0);
}

__device__ __forceinline__ float bf16_rne(float v) {
    unsigned u = __float_as_uint(v);
    unsigned r = (u + 0x7fffu + ((u >> 16) & 1u)) & 0xffff0000u;
    return __uint_as_float(r);
}

// ---------------------------------------------------------------------------
// Convert+swizzle one 64k x 128n tile into B-operand cells (round-0 variant,
// best measured of 4 structures).  LDS f32 [k][n] stride 130 (=2 mod 4):
// float2 writes and b32 column reads are both uniform <=2-way on banks.
__global__ __launch_bounds__(256) void moe_convert_kernel(
    const float* __restrict__ w1, const float* __restrict__ w2,
    const float* __restrict__ w3, _Float16* __restrict__ w1s,
    _Float16* __restrict__ w2s, _Float16* __restrict__ w3s)
{
    const int bid = blockIdx.x;          // 0..4607
    const float* src; _Float16* dst; int N, KBc, ngrp, kgrp;
    if (bid < 1536) {
        const int e = bid / 192, tile = bid % 192;
        src = w1 + (size_t)e * DIM * HID; dst = w1s + (size_t)e * NB1 * KB1 * 512;
        N = HID; KBc = KB1; ngrp = tile & 15; kgrp = tile >> 4;
    } else if (bid < 3072) {
        const int r = bid - 1536, e = r / 192, tile = r % 192;
        src = w2 + (size_t)e * DIM * HID; dst = w2s + (size_t)e * NB1 * KB1 * 512;
        N = HID; KBc = KB1; ngrp = tile & 15; kgrp = tile >> 4;
    } else {
        const int r = bid - 3072, e = r / 192, tile = r % 192;
        src = w3 + (size_t)e * HID * DIM; dst = w3s + (size_t)e * NB2 * KB2 * 512;
        N = DIM; KBc = KB2; ngrp = tile % 6; kgrp = tile / 6;
    }

    __shared__ float Lt[64 * 130];
    const int t  = threadIdx.x;
    const int c4 = (t & 31) * 4;         // f32 col within 128
    const int r0 = (t >> 5) * 8;         // first of 8 k-rows
    const float* p = src + (size_t)(kgrp * 64 + r0) * N + ngrp * 128 + c4;
    float4 v[8];
#pragma unroll
    for (int j = 0; j < 8; ++j) v[j] = *(const float4*)(p + (size_t)j * N);
#pragma unroll
    for (int j = 0; j < 8; ++j) {
        float* row = &Lt[(r0 + j) * 130 + c4];
        *(float2*)(row)     = make_float2(v[j].x, v[j].y);
        *(float2*)(row + 2) = make_float2(v[j].z, v[j].w);
    }
    __syncthreads();

    const int l = t & 63, w = t >> 6;
    const int fr = l & 15, fq = l >> 4;
#pragma unroll
    for (int i = 0; i < 4; ++i) {
        const int cell = w * 4 + i;      // 16 cells: 2 kbl x 8 nbl
        const int kbl = cell >> 3, nbl = cell & 7;
        f16x8 h;
#pragma unroll
        for (int j = 0; j < 8; ++j)
            h[j] = (_Float16)Lt[(kbl * 32 + fq * 8 + j) * 130 + nbl * 16 + fr];
        const int nb = ngrp * 8 + nbl, kb = kgrp * 2 + kbl;
        *(f16x8*)(dst + ((size_t)nb * KBc + kb) * 512 + l * 8) = h;
    }
}

// ---------------------------------------------------------------------------
// Router phase A: one wave per token, NO atomics.  Lane l computes the f64
// partial for expert e=l>>3 over contiguous dims (l&7)*96..+95; reduce over
// dim-groups (3 f64 shuffles); butterflies over 8/16/32 give global max /
// argmax (lowest-index tie-break) / softmax denom.  Writes probs, maxind.
__global__ __launch_bounds__(256) void moe_router_kernel(
    const float* __restrict__ X, const float* __restrict__ rw,
    const float* __restrict__ rb, float* __restrict__ probs,
    int* __restrict__ maxind)
{
    const int t = blockIdx.x * 4 + (threadIdx.x >> 6);
    const int l = threadIdx.x & 63;
    const int e = l >> 3;                 // this lane's expert
    const int g = l & 7;                  // dim-chunk
    const float* x = X + (size_t)t * DIM + g * 96;
    const float* w = rw + e;

    double s0 = 0.0, s1 = 0.0;
#pragma unroll
    for (int j4 = 0; j4 < 24; ++j4) {
        const float4 xv = *(const float4*)(x + j4 * 4);
        const int d = (g * 96 + j4 * 4) * NE;
        s0 += (double)xv.x * (double)w[d];
        s1 += (double)xv.y * (double)w[d + NE];
        s0 += (double)xv.z * (double)w[d + 2 * NE];
        s1 += (double)xv.w * (double)w[d + 3 * NE];
    }
    double s = s0 + s1;
    s += __shfl_xor(s, 1, 64);
    s += __shfl_xor(s, 2, 64);
    s += __shfl_xor(s, 4, 64);
    s += (double)rb[e];

    double m = s; int mi = e;
#pragma unroll
    for (int o = 8; o <= 32; o <<= 1) {
        const double om = __shfl_xor(m, o, 64);
        const int   omi = __shfl_xor(mi, o, 64);
        if (om > m || (om == m && omi < mi)) { m = om; mi = omi; }
    }
    float ex = __expf((float)(s - m));
#pragma unroll
    for (int o = 8; o <= 32; o <<= 1) ex += __shfl_xor(ex, o, 64);

    if (l == 0) { probs[t] = 1.0f / ex; maxind[t] = mi; }
}

// ---------------------------------------------------------------------------
// Router phase B: one block per expert.  Ballot-based stream compaction of
// maxind -> lists[e] (token-sorted), counts[e].  No global atomics.
__global__ __launch_bounds__(256) void moe_lists_kernel(
    const int* __restrict__ maxind, int* __restrict__ counts,
    int* __restrict__ lists)
{
    const int e = blockIdx.x;
    const int tid = threadIdx.x, wid = tid >> 6, lane = tid & 63;
    __shared__ int wsum[4];
    int* dst = lists + e * T_TOK;
    int base = 0;
    for (int t0 = 0; t0 < T_TOK; t0 += 256) {
        const int t = t0 + tid;
        const bool pred = (maxind[t] == e);
        const unsigned long long bal = __ballot(pred);
        const int prefix = __popcll(bal & ((1ull << lane) - 1ull));
        if (lane == 0) wsum[wid] = __popcll(bal);
        __syncthreads();
        int woff = 0;
#pragma unroll
        for (int w2 = 0; w2 < 4; ++w2)
            if (w2 < wid) woff += wsum[w2];
        const int tot = wsum[0] + wsum[1] + wsum[2] + wsum[3];
        if (pred) dst[base + woff + prefix] = t;
        base += tot;
        __syncthreads();                  // wsum reused next iteration
    }
    if (tid == 0) counts[e] = base;
}

// ---------------------------------------------------------------------------
// Gather X rows per expert into A-operand cells (f16), zero-padding rows
// beyond cnt up to the 64-row tile boundary.
__global__ __launch_bounds__(256) void moe_gather_kernel(
    const float* __restrict__ X, const int* __restrict__ lists,
    const int* __restrict__ counts, _Float16* __restrict__ Ag)
{
    const int e = blockIdx.z;
    int cnt = counts[e]; if (cnt > ECAP) cnt = ECAP;
    const int mgrp = blockIdx.y;
    if (mgrp * 64 >= ((cnt + 63) & ~63)) return;
    const int t = threadIdx.x, w = t >> 6, l = t & 63;
    const int mb = mgrp * 4 + w;
    const int m  = mb * 16 + (l & 15);
    const bool valid = (m < cnt);
    const int tok = valid ? lists[e * T_TOK + m] : 0;
    const float* xr = X + (size_t)tok * DIM + (l >> 4) * 8;
#pragma unroll
    for (int i = 0; i < 4; ++i) {
        const int kb = blockIdx.x * 4 + i;
        float4 a = make_float4(0.f, 0.f, 0.f, 0.f), b = a;
        if (valid) {
            a = *(const float4*)(xr + kb * 32);
            b = *(const float4*)(xr + kb * 32 + 4);
        }
        f16x8 h;
        h[0] = (_Float16)a.x; h[1] = (_Float16)a.y; h[2] = (_Float16)a.z; h[3] = (_Float16)a.w;
        h[4] = (_Float16)b.x; h[5] = (_Float16)b.y; h[6] = (_Float16)b.z; h[7] = (_Float16)b.w;
        *(f16x8*)(Ag + ((size_t)(e * MBC + mb) * KB1 + kb) * 512 + l * 8) = h;
    }
}

// ---------------------------------------------------------------------------
// GEMM1: block = 128m x 64n (both W1,W2), wave = 64m x 32n.  Per K-step the
// block stages 16 cells (8 A + 4 W1 + 4 W2 = 16 KB) into LDS via
// global_load_lds (wave w stages cells 4w..4w+3; dest = uniform cell base +
// lane*16B), double-buffered, ONE barrier per step at the END: loads for
// kb+1 issued before compute of kb stay in flight under ds_read+MFMA and are
// drained by the barrier's vmcnt(0).
// Epilogue: silu(h1)*h2 -> f16; transpose buffer ALIASES Ls.
__global__ __launch_bounds__(256, 4) void moe_gemm1_kernel(
    const _Float16* __restrict__ Ag, const _Float16* __restrict__ w1s,
    const _Float16* __restrict__ w2s, const int* __restrict__ counts,
    _Float16* __restrict__ Hs)
{
    const int e = blockIdx.z;
    int cnt = counts[e]; if (cnt > ECAP) cnt = ECAP;
    const int by = blockIdx.y, bx = blockIdx.x;   // by: 128m, bx: 64n
    if (by * 128 >= cnt) return;
    const int t = threadIdx.x, w = t >> 6, l = t & 63;
    const int wm = w & 1, wn = w >> 1;

    __shared__ _Float16 Ls[2][16 * 512];          // 32 KB staging (epilogue aliases)

    // staging sources: wave w owns cells 4w..4w+3
    //   cells 0-7: A (m-cells by*8+c); 8-11: W1 n-cells bx*4+(c-8); 12-15: W2
    const int c0s = w * 4;
    const _Float16* gsrc[4];
#pragma unroll
    for (int i = 0; i < 4; ++i) {
        const int c = c0s + i;
        if (c < 8)
            gsrc[i] = Ag  + ((size_t)((e * MBC + by * 8 + c) * KB1)) * 512;
        else if (c < 12)
            gsrc[i] = w1s + ((size_t)((e * NB1 + bx * 4 + (c - 8)) * KB1)) * 512;
        else
            gsrc[i] = w2s + ((size_t)((e * NB1 + bx * 4 + (c - 12)) * KB1)) * 512;
        gsrc[i] += (size_t)l * 8;                 // per-lane 16 B
    }

    f32x4 acc1[4][2], acc2[4][2];
    const f32x4 zero = {0.f, 0.f, 0.f, 0.f};
#pragma unroll
    for (int i = 0; i < 4; ++i)
#pragma unroll
        for (int j = 0; j < 2; ++j) { acc1[i][j] = zero; acc2[i][j] = zero; }

    auto STAGE = [&](int kb, _Float16* Lb) {
#pragma unroll
        for (int i = 0; i < 4; ++i)
            gload_lds16(gsrc[i] + (size_t)kb * 512, Lb + (c0s + i) * 512);
    };

    STAGE(0, &Ls[0][0]);
    __syncthreads();                              // buffer 0 ready
    for (int kb = 0; kb < KB1; ++kb) {
        _Float16* Lb = &Ls[kb & 1][0];
        if (kb + 1 < KB1) STAGE(kb + 1, &Ls[(kb + 1) & 1][0]);  // in flight

        f16x8 a[4], p[2], q[2];
#pragma unroll
        for (int i = 0; i < 4; ++i)
            a[i] = *(const f16x8*)(Lb + (wm * 4 + i) * 512 + l * 8);
#pragma unroll
        for (int j = 0; j < 2; ++j) {
            p[j] = *(const f16x8*)(Lb + (8  + wn * 2 + j) * 512 + l * 8);
            q[j] = *(const f16x8*)(Lb + (12 + wn * 2 + j) * 512 + l * 8);
        }
#pragma unroll
        for (int i = 0; i < 4; ++i)
#pragma unroll
            for (int j = 0; j < 2; ++j) {
                acc1[i][j] = __builtin_amdgcn_mfma_f32_16x16x32_f16(a[i], p[j], acc1[i][j], 0, 0, 0);
                acc2[i][j] = __builtin_amdgcn_mfma_f32_16x16x32_f16(a[i], q[j], acc2[i][j], 0, 0, 0);
            }
        __syncthreads();                          // drains next-buffer loads
    }

    // epilogue: silu(h1)*h2 -> f16; C-layout -> A-layout via per-wave LDS
    // region aliased onto Ls (64 rows x 40 f16 = 5120 B per wave).
    _Float16* Ep = &Ls[0][0] + (size_t)w * (64 * 40);
    const int fq = l >> 4, fr = l & 15;
#pragma unroll
    for (int i = 0; i < 4; ++i)
#pragma unroll
        for (int j = 0; j < 2; ++j)
#pragma unroll
            for (int r = 0; r < 4; ++r) {
                const float h1 = acc1[i][j][r], h2 = acc2[i][j][r];
                const float s  = h1 / (1.f + __expf(-h1)) * h2;
                Ep[(i * 16 + fq * 4 + r) * 40 + j * 16 + fr] = (_Float16)s;
            }
    __syncthreads();
    const int kbH = bx * 2 + wn;         // this wave's 32-wide hid cell
#pragma unroll
    for (int i = 0; i < 4; ++i) {
        f16x8 v = *(const f16x8*)&Ep[(i * 16 + fr) * 40 + fq * 8];
        *(f16x8*)(Hs + ((size_t)((e * MBC + by * 8 + wm * 4 + i) * KB2 + kbH)) * 512 + l * 8) = v;
    }
}

// ---------------------------------------------------------------------------
// GEMM2: block = 64m x 128n, wave = 64m x 32n, K=2048.  W3 cells wave-private
// -> direct global, register double-buffered (named vB0/vB1).  A cells shared
// by all 4 waves -> LDS via global_load_lds (2 k-cells x 4 m-cells = 8 KB,
// dbuf), one barrier per 2 K-steps at the END of the step.
// Epilogue: bf16_rne(acc) * prob, scatter f32 by token.
__global__ __launch_bounds__(256, 4) void moe_gemm2_kernel(
    const _Float16* __restrict__ Hs, const _Float16* __restrict__ w3s,
    const int* __restrict__ lists, const int* __restrict__ counts,
    const float* __restrict__ probs, float* __restrict__ out)
{
    const int e = blockIdx.z;
    int cnt = counts[e]; if (cnt > ECAP) cnt = ECAP;
    const int by = blockIdx.y, bx = blockIdx.x;   // by: 64m, bx: 128n
    if (by * 64 >= cnt) return;
    const int t = threadIdx.x, w = t >> 6, l = t & 63;

    __shared__ _Float16 La[2][8 * 512];           // 16 KB: 2 k-cells x 4 m-cells

    // A staging source: wave w stages m-cell w (for both k-cells of a step)
    const _Float16* Asrc = Hs + ((size_t)((e * MBC + by * 4 + w) * KB2)) * 512 + l * 8;
    const int nb0 = e * NB2 + bx * 8 + w * 2;
    const _Float16* Bb = w3s + ((size_t)nb0 * KB2) * 512 + l * 8;

    f32x4 acc[4][2];
    const f32x4 zero = {0.f, 0.f, 0.f, 0.f};
#pragma unroll
    for (int i = 0; i < 4; ++i) { acc[i][0] = zero; acc[i][1] = zero; }

    f16x8 vB0[4], vB1[4];    // W3 frags, double-buffered: [u*2+j]

    auto STAGE_A = [&](int s, _Float16* Lb) {
        gload_lds16(Asrc + (size_t)(2 * s)     * 512, Lb +      w  * 512);
        gload_lds16(Asrc + (size_t)(2 * s + 1) * 512, Lb + (4 + w) * 512);
    };
    auto GB = [&](f16x8* vB, int s) {
#pragma unroll
        for (int u = 0; u < 2; ++u)
#pragma unroll
            for (int j = 0; j < 2; ++j)
                vB[u * 2 + j] = *(const f16x8*)(Bb + ((size_t)(j * KB2 + 2 * s + u)) * 512);
    };
    auto STEP = [&](int s, const f16x8* curB, f16x8* nxtB,
                    _Float16* Lb, _Float16* Ln) {
        if (s + 1 < KB2 / 2) { STAGE_A(s + 1, Ln); GB(nxtB, s + 1); }
#pragma unroll
        for (int u = 0; u < 2; ++u) {
            f16x8 a[4];
#pragma unroll
            for (int i = 0; i < 4; ++i)
                a[i] = *(const f16x8*)(Lb + (u * 4 + i) * 512 + l * 8);
#pragma unroll
            for (int i = 0; i < 4; ++i)
#pragma unroll
                for (int j = 0; j < 2; ++j)
                    acc[i][j] = __builtin_amdgcn_mfma_f32_16x16x32_f16(a[i], curB[u * 2 + j], acc[i][j], 0, 0, 0);
        }
        __syncthreads();                          // drains next-buffer loads
    };

    STAGE_A(0, &La[0][0]); GB(vB0, 0);
    __syncthreads();                              // buffer 0 ready
    for (int s2 = 0; s2 < KB2 / 2; s2 += 2) {     // 32 steps, unroll-2 for static vB
        STEP(s2,     vB0, vB1, &La[0][0], &La[1][0]);
        STEP(s2 + 1, vB1, vB0, &La[1][0], &La[0][0]);
    }

    const int* list = lists + e * T_TOK;
    const int fq = l >> 4, fr = l & 15;
    const int c0 = bx * 128 + w * 32;
#pragma unroll
    for (int i = 0; i < 4; ++i)
#pragma unroll
        for (int r = 0; r < 4; ++r) {
            const int m = by * 64 + i * 16 + fq * 4 + r;
            if (m < cnt) {
                const int tok = list[m];
                const float pb = probs[tok];
                float* orow = out + (size_t)tok * DIM + c0 + fr;
                orow[0]  = bf16_rne(acc[i][0][r]) * pb;
                orow[16] = bf16_rne(acc[i][1][r]) * pb;
            }
        }
}

// ---------------------------------------------------------------------------
extern "C" void kernel_launch(void* const* d_in, const int* in_sizes, int n_in,
                              void* d_out, int out_size, void* d_ws, size_t ws_size,
                              hipStream_t stream) {
    const float* X  = (const float*)d_in[0];
    const float* rw = (const float*)d_in[1];
    const float* rb = (const float*)d_in[2];
    const float* w1 = (const float*)d_in[3];
    const float* w2 = (const float*)d_in[4];
    const float* w3 = (const float*)d_in[5];
    float* out = (float*)d_out;

    // workspace layout (bytes); total ~121.6 MB
    char* ws = (char*)d_ws;
    int*      counts = (int*)(ws + 0);
    int*      lists  = (int*)(ws + 256);
    float*    probs  = (float*)(ws + 131328);
    const size_t WSZ = 25165824;  // each swizzled weight: 8*NB*KB*512*2 B
    _Float16* w1s = (_Float16*)(ws + 147712);
    _Float16* w2s = (_Float16*)(ws + 147712 + WSZ);
    _Float16* w3s = (_Float16*)(ws + 147712 + 2 * WSZ);
    _Float16* Ag  = (_Float16*)(ws + 147712 + 3 * WSZ);              // 12.6 MB
    _Float16* Hs  = (_Float16*)(ws + 147712 + 3 * WSZ + 12582912);   // 33.6 MB
    // maxind aliases the head of Ag: written by router, fully consumed by
    // moe_lists_kernel BEFORE moe_gather_kernel writes Ag (same stream).
    int* maxind = (int*)Ag;

    hipLaunchKernelGGL(moe_convert_kernel, dim3(4608), dim3(256), 0, stream,
                       w1, w2, w3, w1s, w2s, w3s);
    hipLaunchKernelGGL(moe_router_kernel, dim3(T_TOK / 4), dim3(256), 0, stream,
                       X, rw, rb, probs, maxind);
    hipLaunchKernelGGL(moe_lists_kernel, dim3(NE), dim3(256), 0, stream,
                       maxind, counts, lists);
    hipLaunchKernelGGL(moe_gather_kernel, dim3(6, 16, 8), dim3(256), 0, stream,
                       X, lists, counts, Ag);
    hipLaunchKernelGGL(moe_gemm1_kernel, dim3(32, 8, 8), dim3(256), 0, stream,
                       Ag, w1s, w2s, counts, Hs);
    hipLaunchKernelGGL(moe_gemm2_kernel, dim3(6, 16, 8), dim3(256), 0, stream,
                       Hs, w3s, lists, counts, probs, out);
}